// Round 3
// baseline (270.330 us; speedup 1.0000x reference)
//
#include <hip/hip_runtime.h>
#include <hip/hip_bf16.h>
#include <stdint.h>

// EdgeDecoder: out = relu(concat(zd[row], zt[col]) @ W1 + b1) @ W2 + b2
// R3: restructured K-loop. A fragments are gathered DIRECTLY from global into
// MFMA operand registers (quad-group of 4 lanes = one 64B line of a gathered
// row), so the random-gather latency is off the barrier path and prefetched one
// kc ahead. B (W1T chunk) is double-buffered in LDS with ONE __syncthreads per
// kc whose vmcnt drain is pre-paid by a full iteration of MFMA compute.
// Each wave owns 32 edges x all 256 cols (acc 2x16 frags); epilogue wave-local.

typedef unsigned short u16;
typedef __attribute__((ext_vector_type(8))) short short8;
typedef __attribute__((ext_vector_type(4))) float f32x4;

#define HDIM 256
#define KDIM 512
#define BM 128     // edges per block (4 waves x 32)
#define BK 64      // k-chunk
#define NKC 8      // KDIM / BK

__device__ __forceinline__ u16 f2bf(float f) {
  union { float f; uint32_t u; } v; v.f = f;
  uint32_t u = v.u;
  return (u16)((u + 0x7fffu + ((u >> 16) & 1u)) >> 16);   // RNE, inputs finite
}

// async global->LDS, 16B per lane; LDS dest must be wave-uniform base (+lane*16)
__device__ __forceinline__ void gl2lds16(const void* g, void* l) {
  __builtin_amdgcn_global_load_lds(
      (const __attribute__((address_space(1))) unsigned int*)g,
      (__attribute__((address_space(3))) unsigned int*)l,
      16, 0, 0);
}

// One prep kernel: blocks 0..31 do a 64x64 LDS-tiled transpose of W1
// (512x256 fp32 -> W1T 256x512 bf16, coalesced both sides); remaining blocks
// grid-stride-convert zd then zt to bf16 via float4 loads.
#define CVT_BLOCKS 4096
__global__ void prep_kernel(const float* __restrict__ zd_f,
                            const float* __restrict__ zt_f,
                            const float* __restrict__ w1,
                            u16* __restrict__ zdb, u16* __restrict__ ztb,
                            u16* __restrict__ w1t, int n4d, int n4t) {
  const int b = blockIdx.x;
  if (b < 32) {
    __shared__ float tile[64][65];
    const int k0 = (b >> 2) * 64, n0 = (b & 3) * 64;
    const int tx = threadIdx.x & 63, ty = threadIdx.x >> 6;
#pragma unroll
    for (int i = ty; i < 64; i += 4)
      tile[i][tx] = w1[(size_t)(k0 + i) * HDIM + n0 + tx];   // coalesced 256B
    __syncthreads();
#pragma unroll
    for (int i = ty; i < 64; i += 4)
      w1t[(size_t)(n0 + i) * KDIM + k0 + tx] = f2bf(tile[tx][i]);  // coalesced
  } else {
    const int idx = (b - 32) * 256 + threadIdx.x;
    const int stride = CVT_BLOCKS * 256;
    for (int i = idx; i < n4d; i += stride) {
      float4 v = ((const float4*)zd_f)[i];
      ushort4 o; o.x = f2bf(v.x); o.y = f2bf(v.y); o.z = f2bf(v.z); o.w = f2bf(v.w);
      ((ushort4*)zdb)[i] = o;
    }
    for (int i = idx; i < n4t; i += stride) {
      float4 v = ((const float4*)zt_f)[i];
      ushort4 o; o.x = f2bf(v.x); o.y = f2bf(v.y); o.z = f2bf(v.z); o.w = f2bf(v.w);
      ((ushort4*)ztb)[i] = o;
    }
  }
}

// Main fused kernel. Block = 256 thr (4 waves). Wave w owns edges
// [w*32, w*32+32) x all 256 output cols. K-loop: 8 chunks of BK=64
// (chunks 0-3 from zd[row], 4-7 from zt[col]).
__global__ __launch_bounds__(256, 2) void edge_mlp_kernel(
    const u16* __restrict__ zd, const u16* __restrict__ zt,
    const int* __restrict__ row, const int* __restrict__ col,
    const u16* __restrict__ w1t, const float* __restrict__ b1,
    const float* __restrict__ w2, const float* __restrict__ b2,
    float* __restrict__ out, int E) {
  __shared__ u16 lB[2][HDIM * BK];   // 2 x 32KB double-buffered W1T chunk
                                     // [n][k], 16B-slot XOR-swizzled

  const int tid   = threadIdx.x;
  const int wid   = tid >> 6;
  const int lane  = tid & 63;
  const int colid = lane & 15;
  const int quad  = lane >> 4;
  const int e0    = blockIdx.x * BM;
  const int r8    = lane >> 3;
  const int slog  = ((lane & 7) ^ (r8 & 7)) * 8;   // staging swizzle (elems)
  const int csw   = colid & 7;                     // read-side swizzle key

  // Per-lane A gather bases: lane covers edges (wid*32 + rt*16 + colid).
  const u16* aB[2][2];               // [rt][0=drug half, 1=target half]
#pragma unroll
  for (int rt = 0; rt < 2; ++rt) {
    int ge = min(e0 + wid * 32 + rt * 16 + colid, E - 1);
    aB[rt][0] = zd + (size_t)row[ge] * HDIM;
    aB[rt][1] = zt + (size_t)col[ge] * HDIM;
  }
  // B staging: wave w stages n-rows [w*64, w*64+64) of the kc-chunk.
  const u16* pB = w1t + (size_t)(wid * 64 + r8) * KDIM + slog;

  f32x4 acc[2][16];
#pragma unroll
  for (int rt = 0; rt < 2; ++rt)
#pragma unroll
    for (int ct = 0; ct < 16; ++ct) acc[rt][ct] = f32x4{0.f, 0.f, 0.f, 0.f};

  short8 aCur[2][2], aNxt[2][2];

  // Prologue: A regs for kc=0 (gathers issue first - longest latency),
  // then stage B chunk 0 into buffer 0.
#pragma unroll
  for (int rt = 0; rt < 2; ++rt)
#pragma unroll
    for (int h = 0; h < 2; ++h)
      aCur[rt][h] = *(const short8*)(aB[rt][0] + (quad + 4 * h) * 8);
#pragma unroll
  for (int j = 0; j < 8; ++j)
    gl2lds16(pB + (size_t)j * 8 * KDIM, &lB[0][(wid * 64 + j * 8) * BK]);
  __syncthreads();

#pragma unroll
  for (int kc = 0; kc < NKC; ++kc) {
    // Prefetch kc+1: A gathers into regs, B chunk into the other buffer.
    if (kc + 1 < NKC) {
      const int kn = kc + 1;
#pragma unroll
      for (int rt = 0; rt < 2; ++rt)
#pragma unroll
        for (int h = 0; h < 2; ++h)
          aNxt[rt][h] = *(const short8*)(aB[rt][kn >> 2] + (kn & 3) * BK +
                                         (quad + 4 * h) * 8);
#pragma unroll
      for (int j = 0; j < 8; ++j)
        gl2lds16(pB + (size_t)j * 8 * KDIM + kn * BK,
                 &lB[kn & 1][(wid * 64 + j * 8) * BK]);
    }

    const u16* lb = lB[kc & 1];
#pragma unroll
    for (int h = 0; h < 2; ++h) {
      const int sl = quad + 4 * h;
#pragma unroll
      for (int ct = 0; ct < 16; ++ct) {
        short8 bF = *(const short8*)&lb[(ct * 16 + colid) * BK +
                                        ((sl ^ csw) * 8)];
        acc[0][ct] = __builtin_amdgcn_mfma_f32_16x16x32_bf16(
            aCur[0][h], bF, acc[0][ct], 0, 0, 0);
        acc[1][ct] = __builtin_amdgcn_mfma_f32_16x16x32_bf16(
            aCur[1][h], bF, acc[1][ct], 0, 0, 0);
      }
    }
#pragma unroll
    for (int rt = 0; rt < 2; ++rt)
#pragma unroll
      for (int h = 0; h < 2; ++h) aCur[rt][h] = aNxt[rt][h];
    if (kc + 1 < NKC) __syncthreads();   // drain pre-paid by the MFMA block
  }

  // Epilogue (wave-local): h = relu(acc + b1[n]); out[e] = sum_n h*W2[n] + b2
  // C/D layout: n = ct*16 + colid, e = wid*32 + rt*16 + quad*4 + j
  float b1v[16], w2v[16];
#pragma unroll
  for (int ct = 0; ct < 16; ++ct) {
    b1v[ct] = b1[ct * 16 + colid];
    w2v[ct] = w2[ct * 16 + colid];
  }
  const float bias2 = b2[0];
#pragma unroll
  for (int rt = 0; rt < 2; ++rt)
#pragma unroll
    for (int j = 0; j < 4; ++j) {
      float s = 0.f;
#pragma unroll
      for (int ct = 0; ct < 16; ++ct)
        s += fmaxf(acc[rt][ct][j] + b1v[ct], 0.f) * w2v[ct];
#pragma unroll
      for (int off = 8; off >= 1; off >>= 1)
        s += __shfl_xor(s, off, 16);             // sum over all 256 n
      if (colid == 0) {
        int ge = e0 + wid * 32 + rt * 16 + quad * 4 + j;
        if (ge < E) out[ge] = s + bias2;
      }
    }
}

// Correct-but-slow fp32 fallback (only if ws_size < 36.2MB): 16 edges/block.
__global__ void fallback_kernel(
    const float* __restrict__ zd, const float* __restrict__ zt,
    const int* __restrict__ row, const int* __restrict__ col,
    const float* __restrict__ W1, const float* __restrict__ b1,
    const float* __restrict__ W2, const float* __restrict__ b2,
    float* __restrict__ out, int E) {
  __shared__ float zc[16][512];
  __shared__ float red[4][16];
  const int e0 = blockIdx.x * 16;
  const int tid = threadIdx.x;
  for (int i = tid; i < 16 * 512; i += 256) {
    int e = i >> 9, k = i & 511;
    int ge = min(e0 + e, E - 1);
    zc[e][k] = (k < HDIM) ? zd[(size_t)row[ge] * HDIM + k]
                          : zt[(size_t)col[ge] * HDIM + (k - HDIM)];
  }
  __syncthreads();
  float acc[16];
#pragma unroll
  for (int e = 0; e < 16; ++e) acc[e] = 0.f;
  for (int k = 0; k < KDIM; ++k) {
    float w = W1[k * HDIM + tid];
#pragma unroll
    for (int e = 0; e < 16; ++e) acc[e] += zc[e][k] * w;
  }
  float wv = W2[tid], bv = b1[tid];
  const int lane = tid & 63, wid = tid >> 6;
#pragma unroll
  for (int e = 0; e < 16; ++e) {
    float pv = fmaxf(acc[e] + bv, 0.f) * wv;
#pragma unroll
    for (int off = 32; off >= 1; off >>= 1) pv += __shfl_down(pv, off, 64);
    if (lane == 0) red[wid][e] = pv;
  }
  __syncthreads();
  if (tid < 16) {
    int ge = e0 + tid;
    if (ge < E)
      out[ge] = red[0][tid] + red[1][tid] + red[2][tid] + red[3][tid] + b2[0];
  }
}

extern "C" void kernel_launch(void* const* d_in, const int* in_sizes, int n_in,
                              void* d_out, int out_size, void* d_ws, size_t ws_size,
                              hipStream_t stream) {
  const float* zd_f = (const float*)d_in[0];
  const float* zt_f = (const float*)d_in[1];
  const int*   row  = (const int*)d_in[2];
  const int*   col  = (const int*)d_in[3];
  const float* W1   = (const float*)d_in[4];
  const float* b1   = (const float*)d_in[5];
  const float* W2   = (const float*)d_in[6];
  const float* b2   = (const float*)d_in[7];
  float* out = (float*)d_out;

  const int E  = in_sizes[2];            // 500000
  const int ND = in_sizes[0] / HDIM;     // 50000
  const int NT = in_sizes[1] / HDIM;     // 20000

  size_t off_w1t = 0;                                    // 256KB
  size_t off_zd  = (size_t)KDIM * HDIM * sizeof(u16);
  size_t off_zt  = off_zd + (size_t)ND * HDIM * sizeof(u16);
  size_t need    = off_zt + (size_t)NT * HDIM * sizeof(u16);  // ~36.1MB

  if (ws_size >= need) {
    u16* w1t = (u16*)((char*)d_ws + off_w1t);
    u16* zdb = (u16*)((char*)d_ws + off_zd);
    u16* ztb = (u16*)((char*)d_ws + off_zt);
    int n4d = ND * HDIM / 4, n4t = NT * HDIM / 4;
    prep_kernel<<<32 + CVT_BLOCKS, 256, 0, stream>>>(zd_f, zt_f, W1,
                                                     zdb, ztb, w1t, n4d, n4t);
    edge_mlp_kernel<<<(E + BM - 1) / BM, 256, 0, stream>>>(
        zdb, ztb, row, col, w1t, b1, W2, b2, out, E);
  } else {
    fallback_kernel<<<(E + 15) / 16, 256, 0, stream>>>(
        zd_f, zt_f, row, col, W1, b1, W2, b2, out, E);
  }
}